// Round 5
// baseline (614.111 us; speedup 1.0000x reference)
//
#include <hip/hip_runtime.h>
#include <stdint.h>

#define CC 256
#define HH 80
#define WW 80
#define PP 6400          // 80*80
#define GG 16
#define GNCNT (16*6400)  // per (n,group): 16 channels * 6400 pixels

using frag_ab = __attribute__((ext_vector_type(8))) short;   // 8 bf16 (4 VGPRs)
using frag_cd = __attribute__((ext_vector_type(4))) float;   // 4 fp32
typedef unsigned short u16;

__device__ __forceinline__ float b2f(u16 u) {
    union { float f; uint32_t i; } v; v.i = ((uint32_t)u) << 16; return v.f;
}
__device__ __forceinline__ u16 f2b(float f) {
    uint32_t x = __float_as_uint(f);
    return (u16)((x + 0x7fffu + ((x >> 16) & 1u)) >> 16);  // RNE
}
__device__ __forceinline__ float sigf(float x) { return 1.f / (1.f + __expf(-x)); }

// async global->LDS, 16B per lane: lane i of the wave lands at lds + i*16B.
// gptr is per-lane (gather); lds base must be wave-uniform.
__device__ __forceinline__ void async16(const u16* g, u16* lds) {
    __builtin_amdgcn_global_load_lds(
        (const __attribute__((address_space(1))) void*)g,
        (__attribute__((address_space(3))) void*)lds, 16, 0, 0);
}

// plain fp32 -> bf16 (weights)
__global__ __launch_bounds__(256) void cvt_kernel(const float* __restrict__ src,
                                                  u16* __restrict__ dst, int n4) {
    int i = blockIdx.x * 256 + threadIdx.x;
    if (i < n4) {
        float4 v = ((const float4*)src)[i];
        ushort4 o;
        o.x = f2b(v.x); o.y = f2b(v.y); o.z = f2b(v.z); o.w = f2b(v.w);
        ((ushort4*)dst)[i] = o;
    }
}

// x [n][c][p] fp32 -> Xt [n][p][c] bf16.  64c x 64p tile per block.
__global__ __launch_bounds__(256) void cvtT_kernel(const float* __restrict__ x,
                                                   u16* __restrict__ Xt) {
    __shared__ u16 sT[64 * 72];   // [p][c], pad 64->72
    const int p0 = blockIdx.x * 64, c0 = blockIdx.y * 64, n = blockIdx.z;
    const int t = threadIdx.x;
    {   // phase 1: read x rows (coalesced along p), scatter bf16 into sT[p][c]
        const int cl = t >> 2, pq = t & 3;
        const float* row = x + ((size_t)(n * CC + c0 + cl)) * PP + p0 + pq * 16;
        #pragma unroll
        for (int u = 0; u < 4; u++) {
            float4 v = ((const float4*)(row + u * 4))[0];
            const int pp = pq * 16 + u * 4;
            sT[(pp + 0) * 72 + cl] = f2b(v.x);
            sT[(pp + 1) * 72 + cl] = f2b(v.y);
            sT[(pp + 2) * 72 + cl] = f2b(v.z);
            sT[(pp + 3) * 72 + cl] = f2b(v.w);
        }
    }
    __syncthreads();
    {   // phase 2: write Xt rows (coalesced along c)
        const int pl = t >> 2, cq = t & 3;
        u16* orow = Xt + ((size_t)(n * PP + p0 + pl)) * CC + c0 + cq * 16;
        *(frag_ab*)(orow)     = *(const frag_ab*)(sT + pl * 72 + cq * 16);
        *(frag_ab*)(orow + 8) = *(const frag_ab*)(sT + pl * 72 + cq * 16 + 8);
    }
}

// Out[m][o] = sum_c A[m][c] * W[o][c]; m = n*6400+p.  Tile 64m x 64o, K=256 whole.
// Both operands staged to LDS in exact MFMA fragment order via async
// global_load_lds gathers (all in flight, ONE latency exposure), one barrier,
// then a zero-barrier unrolled K-loop of conflict-free ds_read_b128 + MFMA.
// Each wave owns 16 m-rows; its A slab (and epilogue scratch) is private.
// MODE 0/2: store bf16 + GN stats atomics (slot 0 / 1).  MODE 1: gate epilogue.
template<int MODE>
__global__ __launch_bounds__(256, 2) void gemm_kernel(
    const u16* __restrict__ A,       // [51200][256] bf16
    const u16* __restrict__ Wb,      // [256][256] bf16
    u16* __restrict__ Out,           // [51200][256] bf16
    float* __restrict__ stats,
    const u16* __restrict__ Hb,      // MODE1: h, same layout as A
    const float* __restrict__ Srow,  // MODE1: [8*80][256]
    const float* __restrict__ Scol,  // MODE1: [8*80][256]
    const float* __restrict__ bgate) // MODE1: [256]
{
    // W slabs: (kc,j) -> 1 KB, lane l holds W[o0+j*16+(l&15)][kc*32+(l>>4)*8 ..+8]
    __shared__ __align__(16) u16 sW[32 * 512];   // 32 KB
    // A slabs: (wave,kc) -> 1 KB, lane l holds A[mrow+(l&15)][kc*32+(l>>4)*8 ..+8]
    __shared__ __align__(16) u16 sA[32 * 512];   // 32 KB (reused as epilogue scratch)

    const int t    = threadIdx.x;
    const int lane = t & 63;
    const int wave = t >> 6;
    const int m    = lane & 15;
    const int q    = lane >> 4;
    const int o0   = blockIdx.y * 64;
    const int m0   = blockIdx.x * 64;
    const int mrow = m0 + wave * 16;       // this wave's 16 rows
    const int n    = blockIdx.x / 100;     // 100 blocks of 64 rows per n

    // ---- stage W: 32 slabs split across waves (8 instrs/wave) ----
    #pragma unroll
    for (int u = 0; u < 2; u++) {
        const int kc = wave * 2 + u;
        #pragma unroll
        for (int j = 0; j < 4; j++) {
            const u16* g = Wb + (size_t)(o0 + j * 16 + m) * CC + kc * 32 + q * 8;
            async16(g, &sW[(kc * 4 + j) * 512]);
        }
    }
    // ---- stage A: wave's own 16 rows, 8 slabs ----
    {
        const u16* arow = A + (size_t)(mrow + m) * CC + q * 8;
        #pragma unroll
        for (int kc = 0; kc < 8; kc++)
            async16(arow + kc * 32, &sA[(wave * 8 + kc) * 512]);
    }
    __syncthreads();   // one vmcnt(0) drain for ALL async staging

    frag_cd acc[4];
    #pragma unroll
    for (int j = 0; j < 4; j++)
        #pragma unroll
        for (int k = 0; k < 4; k++) acc[j][k] = 0.f;

    const u16* ab = sA + wave * 8 * 512;
    #pragma unroll
    for (int kc = 0; kc < 8; kc++) {
        frag_ab af = *(const frag_ab*)(ab + kc * 512 + lane * 8);
        #pragma unroll
        for (int j = 0; j < 4; j++) {
            frag_ab wf = *(const frag_ab*)(sW + (kc * 4 + j) * 512 + lane * 8);
            acc[j] = __builtin_amdgcn_mfma_f32_16x16x32_bf16(af, wf, acc[j], 0, 0, 0);
        }
    }
    // no barrier: each wave now reuses ONLY its own sA slab (8 KB) as scratch

    if (MODE == 0 || MODE == 2) {
        float* st = stats + (MODE == 2 ? 256 : 0);
        #pragma unroll
        for (int j = 0; j < 4; j++) {
            float s = 0.f, sq = 0.f;
            #pragma unroll
            for (int r = 0; r < 4; r++) {
                float v = acc[j][r];
                s += v; sq += v * v;
            }
            #pragma unroll
            for (int off = 32; off > 0; off >>= 1) {
                s  += __shfl_down(s, off);
                sq += __shfl_down(sq, off);
            }
            if (lane == 0) {
                const int g = (o0 >> 4) + j;
                atomicAdd(&st[n * GG + g], s);
                atomicAdd(&st[128 + n * GG + g], sq);
            }
        }
        // repack C (16 rows x 64 o) through private slab -> full-line stores
        u16* myT = sA + wave * 4096;   // 8 KB scratch, use 16x72 u16
        #pragma unroll
        for (int j = 0; j < 4; j++)
            #pragma unroll
            for (int r = 0; r < 4; r++)
                myT[(q * 4 + r) * 72 + j * 16 + m] = f2b(acc[j][r]);
        #pragma unroll
        for (int u = 0; u < 2; u++) {
            const int rr = u * 8 + (lane >> 3);
            frag_ab v = *(const frag_ab*)(myT + rr * 72 + (lane & 7) * 8);
            *(frag_ab*)(Out + (size_t)(mrow + rr) * CC + o0 + (lane & 7) * 8) = v;
        }
    } else {
        float* myG = (float*)(sA + wave * 4096);   // 16x72 fp32 = 4.6 KB
        float bg[4];
        #pragma unroll
        for (int j = 0; j < 4; j++) bg[j] = bgate[o0 + j * 16 + m];
        #pragma unroll
        for (int j = 0; j < 4; j++)
            #pragma unroll
            for (int r = 0; r < 4; r++)
                myG[(q * 4 + r) * 72 + j * 16 + m] = sigf(acc[j][r] + bg[j]);
        #pragma unroll
        for (int u = 0; u < 4; u++) {
            const int rr  = u * 4 + (lane >> 4);    // 0..15
            const int col = (lane & 15) * 4;        // 0..60
            float4 g4 = *(const float4*)(myG + rr * 72 + col);
            const int row = mrow + rr;
            const int pl  = row - n * PP;
            const int pr  = pl / WW;
            const int pc  = pl - pr * WW;
            const int o   = o0 + col;
            ushort4 hv = *(const ushort4*)(Hb + (size_t)row * CC + o);
            float4  sr = *(const float4*)(Srow + (size_t)(n * HH + pr) * CC + o);
            float4  sc = *(const float4*)(Scol + (size_t)(n * HH + pc) * CC + o);
            ushort4 ov;
            ov.x = f2b(0.25f * (sr.x + sc.x + 2.f * b2f(hv.x)) * g4.x);
            ov.y = f2b(0.25f * (sr.y + sc.y + 2.f * b2f(hv.y)) * g4.y);
            ov.z = f2b(0.25f * (sr.z + sc.z + 2.f * b2f(hv.z)) * g4.z);
            ov.w = f2b(0.25f * (sr.w + sc.w + 2.f * b2f(hv.w)) * g4.w);
            *(ushort4*)(Out + (size_t)row * CC + o) = ov;
        }
    }
}

// GN1 + SiLU + Srow.  Block per (i-row, n): 80 j x 256 c.
__global__ __launch_bounds__(256) void gn1_kernel(
    const u16* __restrict__ c1, u16* __restrict__ hb,
    float* __restrict__ Srow,
    const float* __restrict__ stats,
    const float* __restrict__ g1, const float* __restrict__ b1)
{
    __shared__ float sred[8 * 256];
    const int i = blockIdx.x, n = blockIdx.y;
    const int t = threadIdx.x;
    const int jg = t >> 5, cc = t & 31;
    const int c8 = cc * 8;
    const int g  = cc >> 1;   // 8c chunk within one 16c group
    const float su   = stats[n * GG + g];
    const float sq   = stats[128 + n * GG + g];
    const float mean = su * (1.f / GNCNT);
    const float var  = sq * (1.f / GNCNT) - mean * mean;
    const float inv  = rsqrtf(var + 1e-5f);
    float a[8], b[8];
    #pragma unroll
    for (int k = 0; k < 8; k++) {
        a[k] = inv * g1[c8 + k];
        b[k] = b1[c8 + k] - mean * a[k];
    }
    float srow8[8];
    #pragma unroll
    for (int k = 0; k < 8; k++) srow8[k] = 0.f;

    const size_t base = (size_t)(n * PP + i * WW) * CC;
    for (int s = 0; s < 10; s++) {
        const int j = jg + s * 8;
        const u16* src = c1 + base + (size_t)j * CC + c8;
        u16*       dst = hb + base + (size_t)j * CC + c8;
        frag_ab v = *(const frag_ab*)src;
        frag_ab o;
        #pragma unroll
        for (int k = 0; k < 8; k++) {
            float xn = b2f((u16)v[k]) * a[k] + b[k];
            float hs = xn * sigf(xn);
            o[k] = (short)f2b(hs);
            srow8[k] += hs;
        }
        *(frag_ab*)dst = o;
    }
    #pragma unroll
    for (int k = 0; k < 8; k++) sred[jg * 256 + c8 + k] = srow8[k];
    __syncthreads();
    {
        const int c = t;
        float s = 0.f;
        #pragma unroll
        for (int k = 0; k < 8; k++) s += sred[k * 256 + c];
        Srow[(size_t)(n * HH + i) * CC + c] = s;
    }
}

// Scol[n][j][c] = sum_i hs[n][i*80+j][c].  Block (jg, iq, n); atomics (Scol pre-zeroed).
__global__ __launch_bounds__(256) void scol_kernel(
    const u16* __restrict__ hb, float* __restrict__ Scol)
{
    const int jg = blockIdx.x, iq = blockIdx.y, n = blockIdx.z;
    const int t = threadIdx.x;
    const int js = t >> 5, cc = t & 31;
    const int j = jg * 8 + js, c8 = cc * 8;
    float acc8[8];
    #pragma unroll
    for (int k = 0; k < 8; k++) acc8[k] = 0.f;
    for (int s = 0; s < 20; s++) {
        const int i = iq * 20 + s;
        frag_ab v = *(const frag_ab*)(hb + (size_t)(n * PP + i * WW + j) * CC + c8);
        #pragma unroll
        for (int k = 0; k < 8; k++) acc8[k] += b2f((u16)v[k]);
    }
    float* dst = Scol + (size_t)(n * HH + j) * CC + c8;
    #pragma unroll
    for (int k = 0; k < 8; k++) atomicAdd(&dst[k], acc8[k]);
}

// depthwise 3x3 zero-pad in [p][c] layout.  Block (i, chalf, n).
__global__ __launch_bounds__(256) void dw_kernel(
    const u16* __restrict__ gin, u16* __restrict__ dout,
    const float* __restrict__ wdw)
{
    __shared__ float sw[1152];   // 128 c * 9
    const int i = blockIdx.x, chalf = blockIdx.y, n = blockIdx.z;
    const int t = threadIdx.x;
    for (int u = t; u < 1152; u += 256) sw[u] = wdw[chalf * 1152 + u];
    __syncthreads();

    const int jg = t >> 5, cc = t & 31;
    const int gc = chalf * 128 + cc * 4;   // global c of 4-chunk
    float wl[4][9];
    #pragma unroll
    for (int cl = 0; cl < 4; cl++)
        #pragma unroll
        for (int k = 0; k < 9; k++) wl[cl][k] = sw[(cc * 4 + cl) * 9 + k];

    const size_t nbase = (size_t)n * PP * CC;
    for (int s = 0; s < 10; s++) {
        const int j = jg + s * 8;
        float acc4[4] = {0.f, 0.f, 0.f, 0.f};
        #pragma unroll
        for (int di = -1; di <= 1; di++) {
            const int ii = i + di;
            if (ii < 0 || ii >= HH) continue;
            #pragma unroll
            for (int dj = -1; dj <= 1; dj++) {
                const int jj = j + dj;
                if (jj < 0 || jj >= WW) continue;
                ushort4 v = *(const ushort4*)(gin + nbase + (size_t)(ii * WW + jj) * CC + gc);
                const int k = (di + 1) * 3 + (dj + 1);
                acc4[0] += wl[0][k] * b2f(v.x);
                acc4[1] += wl[1][k] * b2f(v.y);
                acc4[2] += wl[2][k] * b2f(v.z);
                acc4[3] += wl[3][k] * b2f(v.w);
            }
        }
        ushort4 o;
        o.x = f2b(acc4[0]); o.y = f2b(acc4[1]); o.z = f2b(acc4[2]); o.w = f2b(acc4[3]);
        *(ushort4*)(dout + nbase + (size_t)(i * WW + j) * CC + gc) = o;
    }
}

// GN2 + SiLU + transpose-out: Y [n][p][c] bf16 -> out [n][c][p] fp32.  64p x 64c tile.
__global__ __launch_bounds__(256) void gn2T_kernel(
    const u16* __restrict__ Y, float* __restrict__ out,
    const float* __restrict__ stats,
    const float* __restrict__ g2, const float* __restrict__ b2v)
{
    __shared__ u16 sT[64 * 72];
    const int p0 = blockIdx.x * 64, c0 = blockIdx.y * 64, n = blockIdx.z;
    const int t = threadIdx.x;
    {   // phase 1: read Y rows (coalesced along c)
        const int pl = t >> 2, cq = t & 3;
        const u16* row = Y + (size_t)(n * PP + p0 + pl) * CC + c0 + cq * 16;
        *(frag_ab*)(sT + pl * 72 + cq * 16)     = *(const frag_ab*)(row);
        *(frag_ab*)(sT + pl * 72 + cq * 16 + 8) = *(const frag_ab*)(row + 8);
    }
    __syncthreads();
    {   // phase 2: per-c affine + silu, write out rows (coalesced along p)
        const int cl = t >> 2, pq = t & 3;
        const int c = c0 + cl, g = c >> 4;
        const float su   = stats[256 + n * GG + g];
        const float sq   = stats[384 + n * GG + g];
        const float mean = su * (1.f / GNCNT);
        const float var  = sq * (1.f / GNCNT) - mean * mean;
        const float inv  = rsqrtf(var + 1e-5f);
        const float a    = inv * g2[c];
        const float b    = b2v[c] - mean * a;
        float* orow = out + (size_t)(n * CC + c) * PP + p0 + pq * 16;
        #pragma unroll
        for (int u4 = 0; u4 < 4; u4++) {
            float4 o;
            float* op = (float*)&o;
            #pragma unroll
            for (int e = 0; e < 4; e++) {
                const int pp = pq * 16 + u4 * 4 + e;
                float xn = b2f(sT[pp * 72 + cl]) * a + b;
                op[e] = xn * sigf(xn);
            }
            ((float4*)(orow + u4 * 4))[0] = o;
        }
    }
}

extern "C" void kernel_launch(void* const* d_in, const int* in_sizes, int n_in,
                              void* d_out, int out_size, void* d_ws, size_t ws_size,
                              hipStream_t stream)
{
    const float* x      = (const float*)d_in[0];
    const float* w_pre  = (const float*)d_in[1];
    const float* g1     = (const float*)d_in[2];
    const float* b1     = (const float*)d_in[3];
    const float* w_gate = (const float*)d_in[4];
    const float* b_gate = (const float*)d_in[5];
    const float* w_dw   = (const float*)d_in[6];
    const float* w_pw   = (const float*)d_in[7];
    const float* g2     = (const float*)d_in[8];
    const float* b2     = (const float*)d_in[9];
    float* out = (float*)d_out;

    char* ws = (char*)d_ws;
    u16*   wb0   = (u16*)(ws);                      // 131,072 B
    u16*   wb1   = (u16*)(ws + 131072);             // 131,072 B
    u16*   wb2   = (u16*)(ws + 262144);             // 131,072 B
    u16*   Xt    = (u16*)(ws + 393216);             // 26,214,400 B
    u16*   bufA  = (u16*)(ws + 26607616);           // 26,214,400 B
    u16*   bufB  = (u16*)(ws + 52822016);           // 26,214,400 B
    float* Srow  = (float*)(ws + 79036416);         // 655,360 B
    float* Scol  = (float*)(ws + 79691776);         // 655,360 B
    float* stats = (float*)(ws + 80347136);         // 2,048 B

    hipMemsetAsync(stats, 0, 2048, stream);
    hipMemsetAsync(Scol, 0, 655360, stream);

    cvt_kernel<<<64, 256, 0, stream>>>(w_pre,  wb0, 16384);
    cvt_kernel<<<64, 256, 0, stream>>>(w_gate, wb1, 16384);
    cvt_kernel<<<64, 256, 0, stream>>>(w_pw,   wb2, 16384);
    cvtT_kernel<<<dim3(100, 4, 8), 256, 0, stream>>>(x, Xt);

    dim3 ggrid(800, 4);   // m-tiles(64) x o-tiles(64)
    // conv1 + GN1 stats
    gemm_kernel<0><<<ggrid, 256, 0, stream>>>(Xt, wb0, bufA, stats,
                                              nullptr, nullptr, nullptr, nullptr);
    // GN1 + SiLU + Srow
    gn1_kernel<<<dim3(80, 8), 256, 0, stream>>>(bufA, bufB, Srow, stats, g1, b1);
    // Scol
    scol_kernel<<<dim3(10, 4, 8), 256, 0, stream>>>(bufB, Scol);
    // gate conv + fused-scan gating
    gemm_kernel<1><<<ggrid, 256, 0, stream>>>(bufB, wb1, bufA, stats,
                                              bufB, Srow, Scol, b_gate);
    // depthwise 3x3
    dw_kernel<<<dim3(80, 2, 8), 256, 0, stream>>>(bufA, bufB, w_dw);
    // conv3 + GN2 stats
    gemm_kernel<2><<<ggrid, 256, 0, stream>>>(bufB, wb2, bufA, stats,
                                              nullptr, nullptr, nullptr, nullptr);
    // GN2 + SiLU -> fp32 out (transposed)
    gn2T_kernel<<<dim3(100, 4, 8), 256, 0, stream>>>(bufA, out, stats, g2, b2);
}

// Round 6
// 386.396 us; speedup vs baseline: 1.5893x; 1.5893x over previous
//
#include <hip/hip_runtime.h>
#include <stdint.h>

#define CC 256
#define HH 80
#define WW 80
#define PP 6400          // 80*80
#define GG 16
#define GNCNT (16*6400)  // per (n,group): 16 channels * 6400 pixels
#define SAPAD 272        // sA row stride in u16 (padded 256->272)

using frag_ab = __attribute__((ext_vector_type(8))) short;   // 8 bf16 (4 VGPRs)
using frag_cd = __attribute__((ext_vector_type(4))) float;   // 4 fp32
typedef unsigned short u16;

__device__ __forceinline__ float b2f(u16 u) {
    union { float f; uint32_t i; } v; v.i = ((uint32_t)u) << 16; return v.f;
}
__device__ __forceinline__ u16 f2b(float f) {
    uint32_t x = __float_as_uint(f);
    return (u16)((x + 0x7fffu + ((x >> 16) & 1u)) >> 16);  // RNE
}
__device__ __forceinline__ float sigf(float x) { return 1.f / (1.f + __expf(-x)); }

// plain fp32 -> bf16 (weights)
__global__ __launch_bounds__(256) void cvt_kernel(const float* __restrict__ src,
                                                  u16* __restrict__ dst, int n4) {
    int i = blockIdx.x * 256 + threadIdx.x;
    if (i < n4) {
        float4 v = ((const float4*)src)[i];
        ushort4 o;
        o.x = f2b(v.x); o.y = f2b(v.y); o.z = f2b(v.z); o.w = f2b(v.w);
        ((ushort4*)dst)[i] = o;
    }
}

// x [n][c][p] fp32 -> Xt [n][p][c] bf16.  64c x 64p tile per block.
__global__ __launch_bounds__(256) void cvtT_kernel(const float* __restrict__ x,
                                                   u16* __restrict__ Xt) {
    __shared__ u16 sT[64 * 72];   // [p][c], pad 64->72
    const int p0 = blockIdx.x * 64, c0 = blockIdx.y * 64, n = blockIdx.z;
    const int t = threadIdx.x;
    {   // phase 1: read x rows (coalesced along p), scatter bf16 into sT[p][c]
        const int cl = t >> 2, pq = t & 3;
        const float* row = x + ((size_t)(n * CC + c0 + cl)) * PP + p0 + pq * 16;
        #pragma unroll
        for (int u = 0; u < 4; u++) {
            float4 v = ((const float4*)(row + u * 4))[0];
            const int pp = pq * 16 + u * 4;
            sT[(pp + 0) * 72 + cl] = f2b(v.x);
            sT[(pp + 1) * 72 + cl] = f2b(v.y);
            sT[(pp + 2) * 72 + cl] = f2b(v.z);
            sT[(pp + 3) * 72 + cl] = f2b(v.w);
        }
    }
    __syncthreads();
    {   // phase 2: write Xt rows (coalesced along c)
        const int pl = t >> 2, cq = t & 3;
        u16* orow = Xt + ((size_t)(n * PP + p0 + pl)) * CC + c0 + cq * 16;
        *(frag_ab*)(orow)     = *(const frag_ab*)(sT + pl * 72 + cq * 16);
        *(frag_ab*)(orow + 8) = *(const frag_ab*)(sT + pl * 72 + cq * 16 + 8);
    }
}

// Out[m][o] = sum_c A[m][c] * W[o][c]; m = n*6400+p.
// Block: 64 m-rows x ALL 256 o (A read once).  Per wave: 64-o slice with the
// W fragments held in REGISTERS (32 frag_ab, loaded once, L2-hot, used 4x so
// the scheduler cannot sink them).  A chunk staged to padded LDS via normal
// lane-contiguous vector loads (no gather DMA!), one barrier, then a pure
// LDS+MFMA loop with zero global loads inside.
// MODE 0/2: store bf16 + GN stats atomics (slot 0 / 1).  MODE 1: gate epilogue.
template<int MODE>
__global__ __launch_bounds__(256, 2) void gemm_kernel(
    const u16* __restrict__ A,       // [51200][256] bf16
    const u16* __restrict__ Wb,      // [256][256] bf16
    u16* __restrict__ Out,           // [51200][256] bf16
    float* __restrict__ stats,
    const u16* __restrict__ Hb,      // MODE1: h, same layout as A
    const float* __restrict__ Srow,  // MODE1: [8*80][256]
    const float* __restrict__ Scol,  // MODE1: [8*80][256]
    const float* __restrict__ bgate) // MODE1: [256]
{
    __shared__ __align__(16) u16 sA[64 * SAPAD];   // 34,816 B

    const int t    = threadIdx.x;
    const int lane = t & 63;
    const int wave = t >> 6;
    const int m    = lane & 15;
    const int q    = lane >> 4;
    const int m0   = blockIdx.x * 64;
    const int n    = blockIdx.x / 100;   // 100 blocks of 64 rows per n
    const int o0w  = wave * 64;          // wave's o-slice

    // ---- W fragments -> registers (32 x 16B, independent, L2-hot) ----
    frag_ab wfr[4][8];
    {
        const u16* wl = Wb + (size_t)(o0w + m) * CC + q * 8;
        #pragma unroll
        for (int j = 0; j < 4; j++)
            #pragma unroll
            for (int kc = 0; kc < 8; kc++)
                wfr[j][kc] = *(const frag_ab*)(wl + (size_t)(j * 16) * CC + kc * 32);
    }

    // ---- stage A chunk: 64 rows x 256 c, lane-contiguous loads ----
    {
        const int row = t >> 2, qt = t & 3;
        const u16* g = A + (size_t)(m0 + row) * CC + qt * 64;
        u16* d = sA + row * SAPAD + qt * 64;
        #pragma unroll
        for (int i = 0; i < 8; i++)
            *(frag_ab*)(d + i * 8) = *(const frag_ab*)(g + i * 8);
    }
    __syncthreads();

    frag_cd acc[4][4];   // [msub][j]
    #pragma unroll
    for (int ms = 0; ms < 4; ms++)
        #pragma unroll
        for (int j = 0; j < 4; j++)
            #pragma unroll
            for (int k = 0; k < 4; k++) acc[ms][j][k] = 0.f;

    #pragma unroll
    for (int ms = 0; ms < 4; ms++) {
        #pragma unroll
        for (int kc = 0; kc < 8; kc++) {
            frag_ab af = *(const frag_ab*)(sA + (ms * 16 + m) * SAPAD + kc * 32 + q * 8);
            #pragma unroll
            for (int j = 0; j < 4; j++)
                acc[ms][j] = __builtin_amdgcn_mfma_f32_16x16x32_bf16(af, wfr[j][kc], acc[ms][j], 0, 0, 0);
        }
    }
    __syncthreads();   // all waves done reading sA; reuse as epilogue scratch

    if (MODE == 0 || MODE == 2) {
        float* st = stats + (MODE == 2 ? 256 : 0);
        #pragma unroll
        for (int j = 0; j < 4; j++) {
            float s = 0.f, sq = 0.f;
            #pragma unroll
            for (int ms = 0; ms < 4; ms++)
                #pragma unroll
                for (int r = 0; r < 4; r++) {
                    float v = acc[ms][j][r];
                    s += v; sq += v * v;
                }
            #pragma unroll
            for (int off = 32; off > 0; off >>= 1) {
                s  += __shfl_down(s, off);
                sq += __shfl_down(sq, off);
            }
            if (lane == 0) {
                const int g = (o0w >> 4) + j;
                atomicAdd(&st[n * GG + g], s);
                atomicAdd(&st[128 + n * GG + g], sq);
            }
        }
        // repack per 16-row subtile through private slab -> 16B stores
        u16* myT = sA + wave * 1152;   // 16x72 u16
        #pragma unroll
        for (int ms = 0; ms < 4; ms++) {
            #pragma unroll
            for (int j = 0; j < 4; j++)
                #pragma unroll
                for (int r = 0; r < 4; r++)
                    myT[(q * 4 + r) * 72 + j * 16 + m] = f2b(acc[ms][j][r]);
            #pragma unroll
            for (int u = 0; u < 2; u++) {
                const int rr = u * 8 + (lane >> 3);
                frag_ab v = *(const frag_ab*)(myT + rr * 72 + (lane & 7) * 8);
                *(frag_ab*)(Out + (size_t)(m0 + ms * 16 + rr) * CC + o0w + (lane & 7) * 8) = v;
            }
        }
    } else {
        float* myG = (float*)sA + wave * 1152;   // 16x72 fp32
        float bg[4];
        #pragma unroll
        for (int j = 0; j < 4; j++) bg[j] = bgate[o0w + j * 16 + m];
        #pragma unroll
        for (int ms = 0; ms < 4; ms++) {
            #pragma unroll
            for (int j = 0; j < 4; j++)
                #pragma unroll
                for (int r = 0; r < 4; r++)
                    myG[(q * 4 + r) * 72 + j * 16 + m] = sigf(acc[ms][j][r] + bg[j]);
            #pragma unroll
            for (int u = 0; u < 4; u++) {
                const int rr  = u * 4 + (lane >> 4);
                const int col = (lane & 15) * 4;
                float4 g4 = *(const float4*)(myG + rr * 72 + col);
                const int row = m0 + ms * 16 + rr;
                const int pl  = row - n * PP;
                const int pr  = pl / WW;
                const int pc  = pl - pr * WW;
                const int o   = o0w + col;
                ushort4 hv = *(const ushort4*)(Hb + (size_t)row * CC + o);
                float4  sr = *(const float4*)(Srow + (size_t)(n * HH + pr) * CC + o);
                float4  sc = *(const float4*)(Scol + (size_t)(n * HH + pc) * CC + o);
                ushort4 ov;
                ov.x = f2b(0.25f * (sr.x + sc.x + 2.f * b2f(hv.x)) * g4.x);
                ov.y = f2b(0.25f * (sr.y + sc.y + 2.f * b2f(hv.y)) * g4.y);
                ov.z = f2b(0.25f * (sr.z + sc.z + 2.f * b2f(hv.z)) * g4.z);
                ov.w = f2b(0.25f * (sr.w + sc.w + 2.f * b2f(hv.w)) * g4.w);
                *(ushort4*)(Out + (size_t)row * CC + o) = ov;
            }
        }
    }
}

// GN1 + SiLU + Srow.  Block per (i-row, n): 80 j x 256 c.
__global__ __launch_bounds__(256) void gn1_kernel(
    const u16* __restrict__ c1, u16* __restrict__ hb,
    float* __restrict__ Srow,
    const float* __restrict__ stats,
    const float* __restrict__ g1, const float* __restrict__ b1)
{
    __shared__ float sred[8 * 256];
    const int i = blockIdx.x, n = blockIdx.y;
    const int t = threadIdx.x;
    const int jg = t >> 5, cc = t & 31;
    const int c8 = cc * 8;
    const int g  = cc >> 1;   // 8c chunk within one 16c group
    const float su   = stats[n * GG + g];
    const float sq   = stats[128 + n * GG + g];
    const float mean = su * (1.f / GNCNT);
    const float var  = sq * (1.f / GNCNT) - mean * mean;
    const float inv  = rsqrtf(var + 1e-5f);
    float a[8], b[8];
    #pragma unroll
    for (int k = 0; k < 8; k++) {
        a[k] = inv * g1[c8 + k];
        b[k] = b1[c8 + k] - mean * a[k];
    }
    float srow8[8];
    #pragma unroll
    for (int k = 0; k < 8; k++) srow8[k] = 0.f;

    const size_t base = (size_t)(n * PP + i * WW) * CC;
    for (int s = 0; s < 10; s++) {
        const int j = jg + s * 8;
        const u16* src = c1 + base + (size_t)j * CC + c8;
        u16*       dst = hb + base + (size_t)j * CC + c8;
        frag_ab v = *(const frag_ab*)src;
        frag_ab o;
        #pragma unroll
        for (int k = 0; k < 8; k++) {
            float xn = b2f((u16)v[k]) * a[k] + b[k];
            float hs = xn * sigf(xn);
            o[k] = (short)f2b(hs);
            srow8[k] += hs;
        }
        *(frag_ab*)dst = o;
    }
    #pragma unroll
    for (int k = 0; k < 8; k++) sred[jg * 256 + c8 + k] = srow8[k];
    __syncthreads();
    {
        const int c = t;
        float s = 0.f;
        #pragma unroll
        for (int k = 0; k < 8; k++) s += sred[k * 256 + c];
        Srow[(size_t)(n * HH + i) * CC + c] = s;
    }
}

// Scol[n][j][c] = sum_i hs[n][i*80+j][c].  Block (jg, iq, n); atomics (Scol pre-zeroed).
__global__ __launch_bounds__(256) void scol_kernel(
    const u16* __restrict__ hb, float* __restrict__ Scol)
{
    const int jg = blockIdx.x, iq = blockIdx.y, n = blockIdx.z;
    const int t = threadIdx.x;
    const int js = t >> 5, cc = t & 31;
    const int j = jg * 8 + js, c8 = cc * 8;
    float acc8[8];
    #pragma unroll
    for (int k = 0; k < 8; k++) acc8[k] = 0.f;
    for (int s = 0; s < 20; s++) {
        const int i = iq * 20 + s;
        frag_ab v = *(const frag_ab*)(hb + (size_t)(n * PP + i * WW + j) * CC + c8);
        #pragma unroll
        for (int k = 0; k < 8; k++) acc8[k] += b2f((u16)v[k]);
    }
    float* dst = Scol + (size_t)(n * HH + j) * CC + c8;
    #pragma unroll
    for (int k = 0; k < 8; k++) atomicAdd(&dst[k], acc8[k]);
}

// depthwise 3x3 zero-pad in [p][c] layout.  Block (i, chalf, n).
__global__ __launch_bounds__(256) void dw_kernel(
    const u16* __restrict__ gin, u16* __restrict__ dout,
    const float* __restrict__ wdw)
{
    __shared__ float sw[1152];   // 128 c * 9
    const int i = blockIdx.x, chalf = blockIdx.y, n = blockIdx.z;
    const int t = threadIdx.x;
    for (int u = t; u < 1152; u += 256) sw[u] = wdw[chalf * 1152 + u];
    __syncthreads();

    const int jg = t >> 5, cc = t & 31;
    const int gc = chalf * 128 + cc * 4;   // global c of 4-chunk
    float wl[4][9];
    #pragma unroll
    for (int cl = 0; cl < 4; cl++)
        #pragma unroll
        for (int k = 0; k < 9; k++) wl[cl][k] = sw[(cc * 4 + cl) * 9 + k];

    const size_t nbase = (size_t)n * PP * CC;
    for (int s = 0; s < 10; s++) {
        const int j = jg + s * 8;
        float acc4[4] = {0.f, 0.f, 0.f, 0.f};
        #pragma unroll
        for (int di = -1; di <= 1; di++) {
            const int ii = i + di;
            if (ii < 0 || ii >= HH) continue;
            #pragma unroll
            for (int dj = -1; dj <= 1; dj++) {
                const int jj = j + dj;
                if (jj < 0 || jj >= WW) continue;
                ushort4 v = *(const ushort4*)(gin + nbase + (size_t)(ii * WW + jj) * CC + gc);
                const int k = (di + 1) * 3 + (dj + 1);
                acc4[0] += wl[0][k] * b2f(v.x);
                acc4[1] += wl[1][k] * b2f(v.y);
                acc4[2] += wl[2][k] * b2f(v.z);
                acc4[3] += wl[3][k] * b2f(v.w);
            }
        }
        ushort4 o;
        o.x = f2b(acc4[0]); o.y = f2b(acc4[1]); o.z = f2b(acc4[2]); o.w = f2b(acc4[3]);
        *(ushort4*)(dout + nbase + (size_t)(i * WW + j) * CC + gc) = o;
    }
}

// GN2 + SiLU + transpose-out: Y [n][p][c] bf16 -> out [n][c][p] fp32.  64p x 64c tile.
__global__ __launch_bounds__(256) void gn2T_kernel(
    const u16* __restrict__ Y, float* __restrict__ out,
    const float* __restrict__ stats,
    const float* __restrict__ g2, const float* __restrict__ b2v)
{
    __shared__ u16 sT[64 * 72];
    const int p0 = blockIdx.x * 64, c0 = blockIdx.y * 64, n = blockIdx.z;
    const int t = threadIdx.x;
    {   // phase 1: read Y rows (coalesced along c)
        const int pl = t >> 2, cq = t & 3;
        const u16* row = Y + (size_t)(n * PP + p0 + pl) * CC + c0 + cq * 16;
        *(frag_ab*)(sT + pl * 72 + cq * 16)     = *(const frag_ab*)(row);
        *(frag_ab*)(sT + pl * 72 + cq * 16 + 8) = *(const frag_ab*)(row + 8);
    }
    __syncthreads();
    {   // phase 2: per-c affine + silu, write out rows (coalesced along p)
        const int cl = t >> 2, pq = t & 3;
        const int c = c0 + cl, g = c >> 4;
        const float su   = stats[256 + n * GG + g];
        const float sq   = stats[384 + n * GG + g];
        const float mean = su * (1.f / GNCNT);
        const float var  = sq * (1.f / GNCNT) - mean * mean;
        const float inv  = rsqrtf(var + 1e-5f);
        const float a    = inv * g2[c];
        const float b    = b2v[c] - mean * a;
        float* orow = out + (size_t)(n * CC + c) * PP + p0 + pq * 16;
        #pragma unroll
        for (int u4 = 0; u4 < 4; u4++) {
            float4 o;
            float* op = (float*)&o;
            #pragma unroll
            for (int e = 0; e < 4; e++) {
                const int pp = pq * 16 + u4 * 4 + e;
                float xn = b2f(sT[pp * 72 + cl]) * a + b;
                op[e] = xn * sigf(xn);
            }
            ((float4*)(orow + u4 * 4))[0] = o;
        }
    }
}

extern "C" void kernel_launch(void* const* d_in, const int* in_sizes, int n_in,
                              void* d_out, int out_size, void* d_ws, size_t ws_size,
                              hipStream_t stream)
{
    const float* x      = (const float*)d_in[0];
    const float* w_pre  = (const float*)d_in[1];
    const float* g1     = (const float*)d_in[2];
    const float* b1     = (const float*)d_in[3];
    const float* w_gate = (const float*)d_in[4];
    const float* b_gate = (const float*)d_in[5];
    const float* w_dw   = (const float*)d_in[6];
    const float* w_pw   = (const float*)d_in[7];
    const float* g2     = (const float*)d_in[8];
    const float* b2     = (const float*)d_in[9];
    float* out = (float*)d_out;

    char* ws = (char*)d_ws;
    u16*   wb0   = (u16*)(ws);                      // 131,072 B
    u16*   wb1   = (u16*)(ws + 131072);             // 131,072 B
    u16*   wb2   = (u16*)(ws + 262144);             // 131,072 B
    u16*   Xt    = (u16*)(ws + 393216);             // 26,214,400 B
    u16*   bufA  = (u16*)(ws + 26607616);           // 26,214,400 B
    u16*   bufB  = (u16*)(ws + 52822016);           // 26,214,400 B
    float* Srow  = (float*)(ws + 79036416);         // 655,360 B
    float* Scol  = (float*)(ws + 79691776);         // 655,360 B
    float* stats = (float*)(ws + 80347136);         // 2,048 B

    hipMemsetAsync(stats, 0, 2048, stream);
    hipMemsetAsync(Scol, 0, 655360, stream);

    cvt_kernel<<<64, 256, 0, stream>>>(w_pre,  wb0, 16384);
    cvt_kernel<<<64, 256, 0, stream>>>(w_gate, wb1, 16384);
    cvt_kernel<<<64, 256, 0, stream>>>(w_pw,   wb2, 16384);
    cvtT_kernel<<<dim3(100, 4, 8), 256, 0, stream>>>(x, Xt);

    // grid: 800 blocks x 64 m-rows, all 256 o per block (A read once)
    // conv1 + GN1 stats
    gemm_kernel<0><<<800, 256, 0, stream>>>(Xt, wb0, bufA, stats,
                                            nullptr, nullptr, nullptr, nullptr);
    // GN1 + SiLU + Srow
    gn1_kernel<<<dim3(80, 8), 256, 0, stream>>>(bufA, bufB, Srow, stats, g1, b1);
    // Scol
    scol_kernel<<<dim3(10, 4, 8), 256, 0, stream>>>(bufB, Scol);
    // gate conv + fused-scan gating
    gemm_kernel<1><<<800, 256, 0, stream>>>(bufB, wb1, bufA, stats,
                                            bufB, Srow, Scol, b_gate);
    // depthwise 3x3
    dw_kernel<<<dim3(80, 2, 8), 256, 0, stream>>>(bufA, bufB, w_dw);
    // conv3 + GN2 stats
    gemm_kernel<2><<<800, 256, 0, stream>>>(bufB, wb2, bufA, stats,
                                            nullptr, nullptr, nullptr, nullptr);
    // GN2 + SiLU -> fp32 out (transposed)
    gn2T_kernel<<<dim3(100, 4, 8), 256, 0, stream>>>(bufA, out, stats, g2, b2);
}